// Round 18
// baseline (167.111 us; speedup 1.0000x reference)
//
#include <hip/hip_runtime.h>
#include <stdint.h>

// GCN 2-layer forward.
// prepw(+gcnt zero) -> bin(standalone) -> gemm1(standalone, W-in-LDS, A-upfront, fp8 out)
//   -> sortsb -> spmm1(fp8 gather) -> gemm2(W-in-LDS, fused relu+b1) -> spmm2+lsm
// record format: x = val bits, y = src | (dst&255)<<17

typedef __attribute__((ext_vector_type(8))) short short8;
typedef __attribute__((ext_vector_type(8))) unsigned short ushort8;
typedef __attribute__((ext_vector_type(4))) float f32x4;
typedef __attribute__((ext_vector_type(2))) float f32x2;

#define BCHUNK 8192
#define LCAP 5632          // per-sub-bucket capacity (mean 4092, large margin)

// f32 -> bf16 bits (RNE)
static __device__ __forceinline__ uint32_t f2bu(float f) {
  uint32_t u = __float_as_uint(f);
  return (u + 0x7FFFu + ((u >> 16) & 1u)) >> 16;
}
static __device__ __forceinline__ float bu2f(unsigned short u) {
  return __uint_as_float(((uint32_t)u) << 16);
}

// 8 fp8(e4m3) -> 8 fma into a[8]
static __device__ __forceinline__ void fma8_fp8(float v, uint2 q, float (&a)[8]) {
  f32x2 p0 = __builtin_amdgcn_cvt_pk_f32_fp8((int)q.x, false);
  f32x2 p1 = __builtin_amdgcn_cvt_pk_f32_fp8((int)q.x, true);
  f32x2 p2 = __builtin_amdgcn_cvt_pk_f32_fp8((int)q.y, false);
  f32x2 p3 = __builtin_amdgcn_cvt_pk_f32_fp8((int)q.y, true);
  a[0] = fmaf(v, p0[0], a[0]); a[1] = fmaf(v, p0[1], a[1]);
  a[2] = fmaf(v, p1[0], a[2]); a[3] = fmaf(v, p1[1], a[3]);
  a[4] = fmaf(v, p2[0], a[4]); a[5] = fmaf(v, p2[1], a[5]);
  a[6] = fmaf(v, p3[0], a[6]); a[7] = fmaf(v, p3[1], a[7]);
}

// ---------------- weight prep (+ gcnt zero, strided — R12 lesson) ----------------
__global__ __launch_bounds__(256) void prepw_k(const float* __restrict__ W1,
                                               const float* __restrict__ W2,
                                               short* __restrict__ W1bt,
                                               short* __restrict__ W2bt,
                                               int* __restrict__ gcnt) {
  if (blockIdx.x == 0)
    for (int t = threadIdx.x; t < 400; t += 256) gcnt[t] = 0;
  int i = blockIdx.x * 256 + threadIdx.x;
  if (i < 256 * 128) {
    int k = i >> 7, c = i & 127;
    W1bt[c * 256 + k] = (short)f2bu(W1[i]);
  }
  if (i < 128 * 64) {
    int k = i >> 6, c = i & 63;
    W2bt[c * 128 + k] = (short)f2bu(W2[i]);
  }
}

// ---------------- bin: standalone (R7-proven), 256-node sub-buckets ----------------
__global__ __launch_bounds__(256) void bin_k(const int* __restrict__ src,
                                             const int* __restrict__ dst,
                                             const float* __restrict__ vals,
                                             int* __restrict__ gcnt,
                                             int2* __restrict__ recs,
                                             int E, int NSB) {
  __shared__ int cnt[400];
  __shared__ int base[400];
  const int tid = threadIdx.x;
  for (int t = tid; t < 400; t += 256) cnt[t] = 0;
  __syncthreads();
  int beg = blockIdx.x * BCHUNK;
  int end = min(beg + BCHUNK, E);
  for (int i = beg + tid; i < end; i += 256) atomicAdd(&cnt[dst[i] >> 8], 1);
  __syncthreads();
  for (int t = tid; t < NSB; t += 256) {
    int c = cnt[t];
    base[t] = c ? atomicAdd(&gcnt[t], c) : 0;
    cnt[t] = 0;
  }
  __syncthreads();
  for (int i = beg + tid; i < end; i += 256) {
    int d = dst[i];
    int s2 = d >> 8;
    int pos = atomicAdd(&cnt[s2], 1);
    int2 r;
    r.x = __float_as_int(vals[i]);
    r.y = src[i] | ((d & 255) << 17);
    recs[(size_t)s2 * LCAP + base[s2] + pos] = r;
  }
}

// ---------------- gemm1: standalone. xw8[M,128](fp8) = X[M,256] @ W1 ----------------
// W staged whole in LDS (67.6 KB, only LDS user); barrier-free K-loop; A-loads upfront.
__global__ __launch_bounds__(512, 4) void gemm1_k(const float* __restrict__ X,
                                                  const short* __restrict__ W1bt,
                                                  uint8_t* __restrict__ X8, int M) {
  __shared__ short Ws[128][264];   // 67.6 KB (stride 132 dwords -> <=2-way aliasing)
  const int tid = threadIdx.x;
  const int lane = tid & 63;
  const int wid = tid >> 6;            // 8 waves, 16 rows each
  const int bm = blockIdx.x * 128;
  const int l15 = lane & 15;
  const int lk8 = (lane >> 4) * 8;

  // stage whole W1bt [128 cols][256 k]: 4096 16B chunks, 8 per thread
#pragma unroll
  for (int i = 0; i < 8; ++i) {
    int idx = tid + i * 512;
    int r = idx >> 5;
    int kq = (idx & 31) * 8;
    *(short8*)&Ws[r][kq] = *(const short8*)&W1bt[r * 256 + kq];
  }

  const int arow = bm + wid * 16 + l15;
  const bool ok = arow < M;
  const float* xr = X + (size_t)arow * 256;

  // issue ALL 16 A-loads up front (static regs)
  float4 a[8][2];
#pragma unroll
  for (int kc = 0; kc < 8; ++kc) {
    if (ok) {
      a[kc][0] = *(const float4*)&xr[kc * 32 + lk8];
      a[kc][1] = *(const float4*)&xr[kc * 32 + lk8 + 4];
    } else {
      a[kc][0] = make_float4(0.f, 0.f, 0.f, 0.f);
      a[kc][1] = make_float4(0.f, 0.f, 0.f, 0.f);
    }
  }

  __syncthreads();                     // Ws ready (the ONLY barrier)

  f32x4 acc[8];
#pragma unroll
  for (int j = 0; j < 8; ++j) acc[j] = (f32x4)0.f;

#pragma unroll
  for (int kc = 0; kc < 8; ++kc) {
    short8 af;
    af[0] = (short)f2bu(a[kc][0].x); af[1] = (short)f2bu(a[kc][0].y);
    af[2] = (short)f2bu(a[kc][0].z); af[3] = (short)f2bu(a[kc][0].w);
    af[4] = (short)f2bu(a[kc][1].x); af[5] = (short)f2bu(a[kc][1].y);
    af[6] = (short)f2bu(a[kc][1].z); af[7] = (short)f2bu(a[kc][1].w);
#pragma unroll
    for (int ni = 0; ni < 8; ++ni) {
      short8 b = *(const short8*)&Ws[ni * 16 + l15][kc * 32 + lk8];
      acc[ni] = __builtin_amdgcn_mfma_f32_16x16x32_bf16(af, b, acc[ni], 0, 0, 0);
    }
  }
  // C/D: col = ni*16 + (lane&15), row = wid*16 + (lane>>4)*4 + j ; fp8 out
#pragma unroll
  for (int j = 0; j < 4; ++j) {
    int row = bm + wid * 16 + (lane >> 4) * 4 + j;
    if (row < M) {
#pragma unroll
      for (int ni = 0; ni < 8; ++ni) {
        int w = __builtin_amdgcn_cvt_pk_fp8_f32(acc[ni][j], 0.f, 0, false);
        X8[(size_t)row * 128 + ni * 16 + l15] = (uint8_t)(w & 0xFF);
      }
    }
  }
}

// ---------------- sortsb: per-sub-bucket counting sort (in place) ----------------
__global__ __launch_bounds__(256) void sortsb_k(int2* __restrict__ recs,
                                                const int* __restrict__ gcnt,
                                                int* __restrict__ begA,
                                                int* __restrict__ endA, int M) {
  __shared__ int2 lrec[LCAP];     // 45 KB
  __shared__ int cnt[256];
  __shared__ int sh[256];
  __shared__ int exc[256];
  __shared__ int cur[256];
  const int s = blockIdx.x;
  const int tid = threadIdx.x;
  int n = gcnt[s];
  if (n > LCAP) n = LCAP;
  int2* g = recs + (size_t)s * LCAP;
  cnt[tid] = 0;
  cur[tid] = 0;
  __syncthreads();
  for (int i = tid; i < n; i += 256) {
    int2 r = g[i];
    lrec[i] = r;
    atomicAdd(&cnt[(r.y >> 17) & 255], 1);
  }
  __syncthreads();
  int v = cnt[tid];
  sh[tid] = v;
  __syncthreads();
#pragma unroll
  for (int o = 1; o < 256; o <<= 1) {
    int t = (tid >= o) ? sh[tid - o] : 0;
    __syncthreads();
    sh[tid] += t;
    __syncthreads();
  }
  exc[tid] = sh[tid] - v;   // exclusive prefix
  __syncthreads();
  for (int i = tid; i < n; i += 256) {
    int2 r = lrec[i];
    int dlo = (r.y >> 17) & 255;
    int p = exc[dlo] + atomicAdd(&cur[dlo], 1);
    g[p] = r;
  }
  int node = s * 256 + tid;
  if (node < M) {
    int b = s * LCAP + exc[tid];
    begA[node] = b;
    endA[node] = b + v;
  }
}

// -------- GEMM2: hwb[M,64](bf16) = relu(Hb+b1) @ W2 — W-in-LDS, barrier-free --------
__global__ __launch_bounds__(512) void gemm2_k(const unsigned short* __restrict__ Hb,
                                               const float* __restrict__ b1,
                                               const short* __restrict__ W2bt,
                                               unsigned short* __restrict__ Yb, int M) {
  __shared__ short Ws[64][136];    // 17.4 KB
  const int tid = threadIdx.x;
  const int lane = tid & 63;
  const int wid = tid >> 6;            // 8 waves, 16 rows each
  const int bm = blockIdx.x * 128;
  const int l15 = lane & 15;
  const int lk8 = (lane >> 4) * 8;

#pragma unroll
  for (int i = 0; i < 2; ++i) {
    int idx = tid + i * 512;
    int r = idx >> 4;
    int kq = (idx & 15) * 8;
    *(short8*)&Ws[r][kq] = *(const short8*)&W2bt[r * 128 + kq];
  }
  __syncthreads();

  const int arow = bm + wid * 16 + l15;
  const bool ok = arow < M;
  const unsigned short* hr = Hb + (size_t)arow * 128;

  f32x4 acc[4];
#pragma unroll
  for (int j = 0; j < 4; ++j) acc[j] = (f32x4)0.f;

#pragma unroll
  for (int kc = 0; kc < 4; ++kc) {
    float4 ba = *(const float4*)&b1[kc * 32 + lk8];
    float4 bb = *(const float4*)&b1[kc * 32 + lk8 + 4];
    short8 af = (short8)0;
    if (ok) {
      ushort8 hv = *(const ushort8*)&hr[kc * 32 + lk8];
      af[0] = (short)f2bu(fmaxf(bu2f(hv[0]) + ba.x, 0.f));
      af[1] = (short)f2bu(fmaxf(bu2f(hv[1]) + ba.y, 0.f));
      af[2] = (short)f2bu(fmaxf(bu2f(hv[2]) + ba.z, 0.f));
      af[3] = (short)f2bu(fmaxf(bu2f(hv[3]) + ba.w, 0.f));
      af[4] = (short)f2bu(fmaxf(bu2f(hv[4]) + bb.x, 0.f));
      af[5] = (short)f2bu(fmaxf(bu2f(hv[5]) + bb.y, 0.f));
      af[6] = (short)f2bu(fmaxf(bu2f(hv[6]) + bb.z, 0.f));
      af[7] = (short)f2bu(fmaxf(bu2f(hv[7]) + bb.w, 0.f));
    }
#pragma unroll
    for (int ni = 0; ni < 4; ++ni) {
      short8 b = *(const short8*)&Ws[ni * 16 + l15][kc * 32 + lk8];
      acc[ni] = __builtin_amdgcn_mfma_f32_16x16x32_bf16(af, b, acc[ni], 0, 0, 0);
    }
  }
#pragma unroll
  for (int j = 0; j < 4; ++j) {
    int row = bm + wid * 16 + (lane >> 4) * 4 + j;
    if (row < M) {
#pragma unroll
      for (int ni = 0; ni < 4; ++ni)
        Yb[(size_t)row * 64 + ni * 16 + l15] = (unsigned short)f2bu(acc[ni][j]);
    }
  }
}

// ---------------- SpMM1: haccb[M,128](bf16) from fp8 gather, 16 thr/node ----------------
__global__ __launch_bounds__(256) void spmm1_k(const int* __restrict__ begA,
                                               const int* __restrict__ endA,
                                               const int2* __restrict__ edges,
                                               const uint8_t* __restrict__ X8,
                                               unsigned short* __restrict__ outb, int M) {
  int node = blockIdx.x * 16 + (threadIdx.x >> 4);
  int g = (threadIdx.x & 15) * 8;
  if (node >= M) return;
  int e = begA[node];
  const int end = endA[node];
  float a0[8], a1[8];
#pragma unroll
  for (int j = 0; j < 8; ++j) { a0[j] = 0.f; a1[j] = 0.f; }
  for (; e + 4 <= end; e += 4) {
    int2 e0 = edges[e], e1 = edges[e + 1], e2 = edges[e + 2], e3 = edges[e + 3];
    float v0 = __int_as_float(e0.x), v1 = __int_as_float(e1.x);
    float v2 = __int_as_float(e2.x), v3 = __int_as_float(e3.x);
    uint2 q0 = *(const uint2*)&X8[(size_t)(e0.y & 0x1FFFF) * 128 + g];
    uint2 q1 = *(const uint2*)&X8[(size_t)(e1.y & 0x1FFFF) * 128 + g];
    uint2 q2 = *(const uint2*)&X8[(size_t)(e2.y & 0x1FFFF) * 128 + g];
    uint2 q3 = *(const uint2*)&X8[(size_t)(e3.y & 0x1FFFF) * 128 + g];
    fma8_fp8(v0, q0, a0);
    fma8_fp8(v1, q1, a1);
    fma8_fp8(v2, q2, a0);
    fma8_fp8(v3, q3, a1);
  }
  for (; e < end; ++e) {
    int2 e0 = edges[e];
    float v0 = __int_as_float(e0.x);
    uint2 q0 = *(const uint2*)&X8[(size_t)(e0.y & 0x1FFFF) * 128 + g];
    fma8_fp8(v0, q0, a0);
  }
  ushort8 o;
#pragma unroll
  for (int j = 0; j < 8; ++j) o[j] = (unsigned short)f2bu(a0[j] + a1[j]);
  *(ushort8*)&outb[(size_t)node * 128 + g] = o;
}

// ---------------- SpMM2 + bias + log_softmax fused, 8 thr/node ----------------
__global__ __launch_bounds__(256) void spmm2_lsm_k(const int* __restrict__ begA,
                                                   const int* __restrict__ endA,
                                                   const int2* __restrict__ edges,
                                                   const unsigned short* __restrict__ Hb,
                                                   const float* __restrict__ b2,
                                                   float* __restrict__ out, int M) {
  int node = blockIdx.x * 32 + (threadIdx.x >> 3);
  int g = (threadIdx.x & 7) * 8;
  if (node >= M) return;
  int e = begA[node];
  const int end = endA[node];
  float a0[8], a1[8];
#pragma unroll
  for (int j = 0; j < 8; ++j) { a0[j] = 0.f; a1[j] = 0.f; }
  for (; e + 4 <= end; e += 4) {
    int2 e0 = edges[e], e1 = edges[e + 1], e2 = edges[e + 2], e3 = edges[e + 3];
    float v0 = __int_as_float(e0.x), v1 = __int_as_float(e1.x);
    float v2 = __int_as_float(e2.x), v3 = __int_as_float(e3.x);
    ushort8 x0 = *(const ushort8*)&Hb[(size_t)(e0.y & 0x1FFFF) * 64 + g];
    ushort8 x1 = *(const ushort8*)&Hb[(size_t)(e1.y & 0x1FFFF) * 64 + g];
    ushort8 x2 = *(const ushort8*)&Hb[(size_t)(e2.y & 0x1FFFF) * 64 + g];
    ushort8 x3 = *(const ushort8*)&Hb[(size_t)(e3.y & 0x1FFFF) * 64 + g];
#pragma unroll
    for (int j = 0; j < 8; ++j) {
      a0[j] = fmaf(v0, bu2f(x0[j]), a0[j]);
      a1[j] = fmaf(v1, bu2f(x1[j]), a1[j]);
      a0[j] = fmaf(v2, bu2f(x2[j]), a0[j]);
      a1[j] = fmaf(v3, bu2f(x3[j]), a1[j]);
    }
  }
  for (; e < end; ++e) {
    int2 e0 = edges[e];
    float v0 = __int_as_float(e0.x);
    ushort8 x0 = *(const ushort8*)&Hb[(size_t)(e0.y & 0x1FFFF) * 64 + g];
#pragma unroll
    for (int j = 0; j < 8; ++j) a0[j] = fmaf(v0, bu2f(x0[j]), a0[j]);
  }
  float v[8];
  float4 ba = *(const float4*)&b2[g];
  float4 bb = *(const float4*)&b2[g + 4];
  v[0] = a0[0] + a1[0] + ba.x; v[1] = a0[1] + a1[1] + ba.y;
  v[2] = a0[2] + a1[2] + ba.z; v[3] = a0[3] + a1[3] + ba.w;
  v[4] = a0[4] + a1[4] + bb.x; v[5] = a0[5] + a1[5] + bb.y;
  v[6] = a0[6] + a1[6] + bb.z; v[7] = a0[7] + a1[7] + bb.w;
  float m = v[0];
#pragma unroll
  for (int j = 1; j < 8; ++j) m = fmaxf(m, v[j]);
#pragma unroll
  for (int o = 1; o < 8; o <<= 1) m = fmaxf(m, __shfl_xor(m, o, 64));
  float s = 0.f;
#pragma unroll
  for (int j = 0; j < 8; ++j) s += expf(v[j] - m);
#pragma unroll
  for (int o = 1; o < 8; o <<= 1) s += __shfl_xor(s, o, 64);
  float lse = m + logf(s);
  float4 r0 = make_float4(v[0] - lse, v[1] - lse, v[2] - lse, v[3] - lse);
  float4 r1 = make_float4(v[4] - lse, v[5] - lse, v[6] - lse, v[7] - lse);
  *(float4*)&out[(size_t)node * 64 + g] = r0;
  *(float4*)&out[(size_t)node * 64 + g + 4] = r1;
}

extern "C" void kernel_launch(void* const* d_in, const int* in_sizes, int n_in,
                              void* d_out, int out_size, void* d_ws, size_t ws_size,
                              hipStream_t stream) {
  const float* x    = (const float*)d_in[0];
  const int*   src  = (const int*)  d_in[1];
  const int*   dst  = (const int*)  d_in[2];
  const float* vals = (const float*)d_in[3];
  const float* W1   = (const float*)d_in[4];
  const float* b1   = (const float*)d_in[5];
  const float* W2   = (const float*)d_in[6];
  const float* b2   = (const float*)d_in[7];
  const int M = in_sizes[0] / 256;   // 100000
  const int E = in_sizes[1];         // 1600000

  const int NSB = (M + 255) >> 8;    // 391 sub-buckets of 256 nodes

  // workspace layout
  int2* recs = (int2*)d_ws;                                  // NSB*LCAP*8B (~17.6MB)
  uint8_t* xw8 = (uint8_t*)(recs + (size_t)NSB * LCAP);      // M*128 fp8 (12.8MB)
  unsigned short* haccb = (unsigned short*)(xw8 + (size_t)M * 128); // M*128 bf16
  unsigned short* hwb   = haccb + (size_t)M * 128;           // M*64 bf16
  int* begA   = (int*)(hwb + (size_t)M * 64);                // M
  int* endA   = begA + M;                                    // M
  int* gcnt   = endA + M;                                    // 400
  short* W1bt = (short*)(gcnt + 400);                        // 256*128
  short* W2bt = W1bt + 256 * 128;                            // 128*64
  float* outf = (float*)d_out;

  const int gbin = (E + BCHUNK - 1) / BCHUNK;                // 196
  const int GB   = (M + 127) / 128;                          // 782

  prepw_k<<<128, 256, 0, stream>>>(W1, W2, W1bt, W2bt, gcnt);
  bin_k<<<gbin, 256, 0, stream>>>(src, dst, vals, gcnt, recs, E, NSB);

  gemm1_k<<<GB, 512, 0, stream>>>(x, W1bt, xw8, M);
  sortsb_k<<<NSB, 256, 0, stream>>>(recs, gcnt, begA, endA, M);

  spmm1_k<<<(M + 15) / 16, 256, 0, stream>>>(begA, endA, recs, xw8, haccb, M);

  gemm2_k<<<GB, 512, 0, stream>>>(haccb, b1, W2bt, hwb, M);
  spmm2_lsm_k<<<(M + 31) / 32, 256, 0, stream>>>(begA, endA, recs, hwb, b2, outf, M);
}

// Round 19
// 145.340 us; speedup vs baseline: 1.1498x; 1.1498x over previous
//
#include <hip/hip_runtime.h>
#include <stdint.h>

// GCN 2-layer forward — best-measured configuration (R16, 145.3 us).
// prepw(+gcnt zero, strided) -> fused[gemm1(W-in-LDS, all-A-loads-upfront) || bin]
//   -> sortsb -> spmm1(fp8 gather) -> gemm2(W-in-LDS, fused relu+b1) -> spmm2+lsm
// record format: x = val bits, y = src | (dst&255)<<17

typedef __attribute__((ext_vector_type(8))) short short8;
typedef __attribute__((ext_vector_type(8))) unsigned short ushort8;
typedef __attribute__((ext_vector_type(4))) float f32x4;
typedef __attribute__((ext_vector_type(2))) float f32x2;

#define BCHUNK 8192
#define LCAP 5632          // per-sub-bucket capacity (mean 4092, large margin)

// f32 -> bf16 bits (RNE)
static __device__ __forceinline__ uint32_t f2bu(float f) {
  uint32_t u = __float_as_uint(f);
  return (u + 0x7FFFu + ((u >> 16) & 1u)) >> 16;
}
static __device__ __forceinline__ float bu2f(unsigned short u) {
  return __uint_as_float(((uint32_t)u) << 16);
}

// 8 fp8(e4m3) -> 8 fma into a[8]
static __device__ __forceinline__ void fma8_fp8(float v, uint2 q, float (&a)[8]) {
  f32x2 p0 = __builtin_amdgcn_cvt_pk_f32_fp8((int)q.x, false);
  f32x2 p1 = __builtin_amdgcn_cvt_pk_f32_fp8((int)q.x, true);
  f32x2 p2 = __builtin_amdgcn_cvt_pk_f32_fp8((int)q.y, false);
  f32x2 p3 = __builtin_amdgcn_cvt_pk_f32_fp8((int)q.y, true);
  a[0] = fmaf(v, p0[0], a[0]); a[1] = fmaf(v, p0[1], a[1]);
  a[2] = fmaf(v, p1[0], a[2]); a[3] = fmaf(v, p1[1], a[3]);
  a[4] = fmaf(v, p2[0], a[4]); a[5] = fmaf(v, p2[1], a[5]);
  a[6] = fmaf(v, p3[0], a[6]); a[7] = fmaf(v, p3[1], a[7]);
}

// ---------------- weight prep (+ gcnt zero, strided — R12 lesson) ----------------
__global__ __launch_bounds__(256) void prepw_k(const float* __restrict__ W1,
                                               const float* __restrict__ W2,
                                               short* __restrict__ W1bt,
                                               short* __restrict__ W2bt,
                                               int* __restrict__ gcnt) {
  if (blockIdx.x == 0)
    for (int t = threadIdx.x; t < 400; t += 256) gcnt[t] = 0;
  int i = blockIdx.x * 256 + threadIdx.x;
  if (i < 256 * 128) {
    int k = i >> 7, c = i & 127;
    W1bt[c * 256 + k] = (short)f2bu(W1[i]);
  }
  if (i < 128 * 64) {
    int k = i >> 6, c = i & 63;
    W2bt[c * 128 + k] = (short)f2bu(W2[i]);
  }
}

// ---------------- fused: gemm1 (blocks < GB) | bin (blocks >= GB) ----------------
// gemm1: xw8[M,128](fp8) = X[M,256] @ W1. W staged whole in LDS once; K-loop
//        barrier-free; all 16 A-loads issued up front.
__global__ __launch_bounds__(512) void fused1_k(const float* __restrict__ X,
                                                const short* __restrict__ W1bt,
                                                uint8_t* __restrict__ X8, int M,
                                                const int* __restrict__ src,
                                                const int* __restrict__ dst,
                                                const float* __restrict__ vals,
                                                int* __restrict__ gcnt,
                                                int2* __restrict__ recs,
                                                int E, int NSB, int GB) {
  __shared__ short Ws[128][264];   // 67.6 KB (stride 132 dwords -> <=2-way aliasing)
  __shared__ int cnt[400];
  __shared__ int base[400];
  const int tid = threadIdx.x;

  if (blockIdx.x >= GB) {
    // ---------------- bin portion ----------------
    for (int t = tid; t < 400; t += 512) cnt[t] = 0;
    __syncthreads();
    int beg = (blockIdx.x - GB) * BCHUNK;
    int end = min(beg + BCHUNK, E);
    for (int i = beg + tid; i < end; i += 512) atomicAdd(&cnt[dst[i] >> 8], 1);
    __syncthreads();
    for (int t = tid; t < NSB; t += 512) {
      int c = cnt[t];
      base[t] = c ? atomicAdd(&gcnt[t], c) : 0;
      cnt[t] = 0;
    }
    __syncthreads();
    for (int i = beg + tid; i < end; i += 512) {
      int d = dst[i];
      int s2 = d >> 8;
      int pos = atomicAdd(&cnt[s2], 1);
      int2 r;
      r.x = __float_as_int(vals[i]);
      r.y = src[i] | ((d & 255) << 17);
      recs[(size_t)s2 * LCAP + base[s2] + pos] = r;
    }
    return;
  }

  // ---------------- gemm1 portion ----------------
  const int lane = tid & 63;
  const int wid = tid >> 6;            // 8 waves, 16 rows each
  const int bm = blockIdx.x * 128;
  const int l15 = lane & 15;
  const int lk8 = (lane >> 4) * 8;

  // stage whole W1bt [128 cols][256 k]: 4096 16B chunks, 8 per thread
#pragma unroll
  for (int i = 0; i < 8; ++i) {
    int idx = tid + i * 512;
    int r = idx >> 5;
    int kq = (idx & 31) * 8;
    *(short8*)&Ws[r][kq] = *(const short8*)&W1bt[r * 256 + kq];
  }

  const int arow = bm + wid * 16 + l15;
  const bool ok = arow < M;
  const float* xr = X + (size_t)arow * 256;

  // issue ALL 16 A-loads up front (static regs)
  float4 a[8][2];
#pragma unroll
  for (int kc = 0; kc < 8; ++kc) {
    if (ok) {
      a[kc][0] = *(const float4*)&xr[kc * 32 + lk8];
      a[kc][1] = *(const float4*)&xr[kc * 32 + lk8 + 4];
    } else {
      a[kc][0] = make_float4(0.f, 0.f, 0.f, 0.f);
      a[kc][1] = make_float4(0.f, 0.f, 0.f, 0.f);
    }
  }

  __syncthreads();                     // Ws ready (the ONLY barrier)

  f32x4 acc[8];
#pragma unroll
  for (int j = 0; j < 8; ++j) acc[j] = (f32x4)0.f;

#pragma unroll
  for (int kc = 0; kc < 8; ++kc) {
    short8 af;
    af[0] = (short)f2bu(a[kc][0].x); af[1] = (short)f2bu(a[kc][0].y);
    af[2] = (short)f2bu(a[kc][0].z); af[3] = (short)f2bu(a[kc][0].w);
    af[4] = (short)f2bu(a[kc][1].x); af[5] = (short)f2bu(a[kc][1].y);
    af[6] = (short)f2bu(a[kc][1].z); af[7] = (short)f2bu(a[kc][1].w);
#pragma unroll
    for (int ni = 0; ni < 8; ++ni) {
      short8 b = *(const short8*)&Ws[ni * 16 + l15][kc * 32 + lk8];
      acc[ni] = __builtin_amdgcn_mfma_f32_16x16x32_bf16(af, b, acc[ni], 0, 0, 0);
    }
  }
  // C/D: col = ni*16 + (lane&15), row = wid*16 + (lane>>4)*4 + j ; fp8 out
#pragma unroll
  for (int j = 0; j < 4; ++j) {
    int row = bm + wid * 16 + (lane >> 4) * 4 + j;
    if (row < M) {
#pragma unroll
      for (int ni = 0; ni < 8; ++ni) {
        int w = __builtin_amdgcn_cvt_pk_fp8_f32(acc[ni][j], 0.f, 0, false);
        X8[(size_t)row * 128 + ni * 16 + l15] = (uint8_t)(w & 0xFF);
      }
    }
  }
}

// ---------------- sortsb: per-sub-bucket counting sort (in place) ----------------
__global__ __launch_bounds__(256) void sortsb_k(int2* __restrict__ recs,
                                                const int* __restrict__ gcnt,
                                                int* __restrict__ begA,
                                                int* __restrict__ endA, int M) {
  __shared__ int2 lrec[LCAP];     // 45 KB
  __shared__ int cnt[256];
  __shared__ int sh[256];
  __shared__ int exc[256];
  __shared__ int cur[256];
  const int s = blockIdx.x;
  const int tid = threadIdx.x;
  int n = gcnt[s];
  if (n > LCAP) n = LCAP;
  int2* g = recs + (size_t)s * LCAP;
  cnt[tid] = 0;
  cur[tid] = 0;
  __syncthreads();
  for (int i = tid; i < n; i += 256) {
    int2 r = g[i];
    lrec[i] = r;
    atomicAdd(&cnt[(r.y >> 17) & 255], 1);
  }
  __syncthreads();
  int v = cnt[tid];
  sh[tid] = v;
  __syncthreads();
#pragma unroll
  for (int o = 1; o < 256; o <<= 1) {
    int t = (tid >= o) ? sh[tid - o] : 0;
    __syncthreads();
    sh[tid] += t;
    __syncthreads();
  }
  exc[tid] = sh[tid] - v;   // exclusive prefix
  __syncthreads();
  for (int i = tid; i < n; i += 256) {
    int2 r = lrec[i];
    int dlo = (r.y >> 17) & 255;
    int p = exc[dlo] + atomicAdd(&cur[dlo], 1);
    g[p] = r;
  }
  int node = s * 256 + tid;
  if (node < M) {
    int b = s * LCAP + exc[tid];
    begA[node] = b;
    endA[node] = b + v;
  }
}

// -------- GEMM2: hwb[M,64](bf16) = relu(Hb+b1) @ W2 — W-in-LDS, barrier-free --------
__global__ __launch_bounds__(512) void gemm2_k(const unsigned short* __restrict__ Hb,
                                               const float* __restrict__ b1,
                                               const short* __restrict__ W2bt,
                                               unsigned short* __restrict__ Yb, int M) {
  __shared__ short Ws[64][136];    // 17.4 KB
  const int tid = threadIdx.x;
  const int lane = tid & 63;
  const int wid = tid >> 6;            // 8 waves, 16 rows each
  const int bm = blockIdx.x * 128;
  const int l15 = lane & 15;
  const int lk8 = (lane >> 4) * 8;

#pragma unroll
  for (int i = 0; i < 2; ++i) {
    int idx = tid + i * 512;
    int r = idx >> 4;
    int kq = (idx & 15) * 8;
    *(short8*)&Ws[r][kq] = *(const short8*)&W2bt[r * 128 + kq];
  }
  __syncthreads();

  const int arow = bm + wid * 16 + l15;
  const bool ok = arow < M;
  const unsigned short* hr = Hb + (size_t)arow * 128;

  f32x4 acc[4];
#pragma unroll
  for (int j = 0; j < 4; ++j) acc[j] = (f32x4)0.f;

#pragma unroll
  for (int kc = 0; kc < 4; ++kc) {
    float4 ba = *(const float4*)&b1[kc * 32 + lk8];
    float4 bb = *(const float4*)&b1[kc * 32 + lk8 + 4];
    short8 af = (short8)0;
    if (ok) {
      ushort8 hv = *(const ushort8*)&hr[kc * 32 + lk8];
      af[0] = (short)f2bu(fmaxf(bu2f(hv[0]) + ba.x, 0.f));
      af[1] = (short)f2bu(fmaxf(bu2f(hv[1]) + ba.y, 0.f));
      af[2] = (short)f2bu(fmaxf(bu2f(hv[2]) + ba.z, 0.f));
      af[3] = (short)f2bu(fmaxf(bu2f(hv[3]) + ba.w, 0.f));
      af[4] = (short)f2bu(fmaxf(bu2f(hv[4]) + bb.x, 0.f));
      af[5] = (short)f2bu(fmaxf(bu2f(hv[5]) + bb.y, 0.f));
      af[6] = (short)f2bu(fmaxf(bu2f(hv[6]) + bb.z, 0.f));
      af[7] = (short)f2bu(fmaxf(bu2f(hv[7]) + bb.w, 0.f));
    }
#pragma unroll
    for (int ni = 0; ni < 4; ++ni) {
      short8 b = *(const short8*)&Ws[ni * 16 + l15][kc * 32 + lk8];
      acc[ni] = __builtin_amdgcn_mfma_f32_16x16x32_bf16(af, b, acc[ni], 0, 0, 0);
    }
  }
#pragma unroll
  for (int j = 0; j < 4; ++j) {
    int row = bm + wid * 16 + (lane >> 4) * 4 + j;
    if (row < M) {
#pragma unroll
      for (int ni = 0; ni < 4; ++ni)
        Yb[(size_t)row * 64 + ni * 16 + l15] = (unsigned short)f2bu(acc[ni][j]);
    }
  }
}

// ---------------- SpMM1: haccb[M,128](bf16) from fp8 gather, 16 thr/node ----------------
__global__ __launch_bounds__(256) void spmm1_k(const int* __restrict__ begA,
                                               const int* __restrict__ endA,
                                               const int2* __restrict__ edges,
                                               const uint8_t* __restrict__ X8,
                                               unsigned short* __restrict__ outb, int M) {
  int node = blockIdx.x * 16 + (threadIdx.x >> 4);
  int g = (threadIdx.x & 15) * 8;
  if (node >= M) return;
  int e = begA[node];
  const int end = endA[node];
  float a0[8], a1[8];
#pragma unroll
  for (int j = 0; j < 8; ++j) { a0[j] = 0.f; a1[j] = 0.f; }
  for (; e + 4 <= end; e += 4) {
    int2 e0 = edges[e], e1 = edges[e + 1], e2 = edges[e + 2], e3 = edges[e + 3];
    float v0 = __int_as_float(e0.x), v1 = __int_as_float(e1.x);
    float v2 = __int_as_float(e2.x), v3 = __int_as_float(e3.x);
    uint2 q0 = *(const uint2*)&X8[(size_t)(e0.y & 0x1FFFF) * 128 + g];
    uint2 q1 = *(const uint2*)&X8[(size_t)(e1.y & 0x1FFFF) * 128 + g];
    uint2 q2 = *(const uint2*)&X8[(size_t)(e2.y & 0x1FFFF) * 128 + g];
    uint2 q3 = *(const uint2*)&X8[(size_t)(e3.y & 0x1FFFF) * 128 + g];
    fma8_fp8(v0, q0, a0);
    fma8_fp8(v1, q1, a1);
    fma8_fp8(v2, q2, a0);
    fma8_fp8(v3, q3, a1);
  }
  for (; e < end; ++e) {
    int2 e0 = edges[e];
    float v0 = __int_as_float(e0.x);
    uint2 q0 = *(const uint2*)&X8[(size_t)(e0.y & 0x1FFFF) * 128 + g];
    fma8_fp8(v0, q0, a0);
  }
  ushort8 o;
#pragma unroll
  for (int j = 0; j < 8; ++j) o[j] = (unsigned short)f2bu(a0[j] + a1[j]);
  *(ushort8*)&outb[(size_t)node * 128 + g] = o;
}

// ---------------- SpMM2 + bias + log_softmax fused, 8 thr/node ----------------
__global__ __launch_bounds__(256) void spmm2_lsm_k(const int* __restrict__ begA,
                                                   const int* __restrict__ endA,
                                                   const int2* __restrict__ edges,
                                                   const unsigned short* __restrict__ Hb,
                                                   const float* __restrict__ b2,
                                                   float* __restrict__ out, int M) {
  int node = blockIdx.x * 32 + (threadIdx.x >> 3);
  int g = (threadIdx.x & 7) * 8;
  if (node >= M) return;
  int e = begA[node];
  const int end = endA[node];
  float a0[8], a1[8];
#pragma unroll
  for (int j = 0; j < 8; ++j) { a0[j] = 0.f; a1[j] = 0.f; }
  for (; e + 4 <= end; e += 4) {
    int2 e0 = edges[e], e1 = edges[e + 1], e2 = edges[e + 2], e3 = edges[e + 3];
    float v0 = __int_as_float(e0.x), v1 = __int_as_float(e1.x);
    float v2 = __int_as_float(e2.x), v3 = __int_as_float(e3.x);
    ushort8 x0 = *(const ushort8*)&Hb[(size_t)(e0.y & 0x1FFFF) * 64 + g];
    ushort8 x1 = *(const ushort8*)&Hb[(size_t)(e1.y & 0x1FFFF) * 64 + g];
    ushort8 x2 = *(const ushort8*)&Hb[(size_t)(e2.y & 0x1FFFF) * 64 + g];
    ushort8 x3 = *(const ushort8*)&Hb[(size_t)(e3.y & 0x1FFFF) * 64 + g];
#pragma unroll
    for (int j = 0; j < 8; ++j) {
      a0[j] = fmaf(v0, bu2f(x0[j]), a0[j]);
      a1[j] = fmaf(v1, bu2f(x1[j]), a1[j]);
      a0[j] = fmaf(v2, bu2f(x2[j]), a0[j]);
      a1[j] = fmaf(v3, bu2f(x3[j]), a1[j]);
    }
  }
  for (; e < end; ++e) {
    int2 e0 = edges[e];
    float v0 = __int_as_float(e0.x);
    ushort8 x0 = *(const ushort8*)&Hb[(size_t)(e0.y & 0x1FFFF) * 64 + g];
#pragma unroll
    for (int j = 0; j < 8; ++j) a0[j] = fmaf(v0, bu2f(x0[j]), a0[j]);
  }
  float v[8];
  float4 ba = *(const float4*)&b2[g];
  float4 bb = *(const float4*)&b2[g + 4];
  v[0] = a0[0] + a1[0] + ba.x; v[1] = a0[1] + a1[1] + ba.y;
  v[2] = a0[2] + a1[2] + ba.z; v[3] = a0[3] + a1[3] + ba.w;
  v[4] = a0[4] + a1[4] + bb.x; v[5] = a0[5] + a1[5] + bb.y;
  v[6] = a0[6] + a1[6] + bb.z; v[7] = a0[7] + a1[7] + bb.w;
  float m = v[0];
#pragma unroll
  for (int j = 1; j < 8; ++j) m = fmaxf(m, v[j]);
#pragma unroll
  for (int o = 1; o < 8; o <<= 1) m = fmaxf(m, __shfl_xor(m, o, 64));
  float s = 0.f;
#pragma unroll
  for (int j = 0; j < 8; ++j) s += expf(v[j] - m);
#pragma unroll
  for (int o = 1; o < 8; o <<= 1) s += __shfl_xor(s, o, 64);
  float lse = m + logf(s);
  float4 r0 = make_float4(v[0] - lse, v[1] - lse, v[2] - lse, v[3] - lse);
  float4 r1 = make_float4(v[4] - lse, v[5] - lse, v[6] - lse, v[7] - lse);
  *(float4*)&out[(size_t)node * 64 + g] = r0;
  *(float4*)&out[(size_t)node * 64 + g + 4] = r1;
}

extern "C" void kernel_launch(void* const* d_in, const int* in_sizes, int n_in,
                              void* d_out, int out_size, void* d_ws, size_t ws_size,
                              hipStream_t stream) {
  const float* x    = (const float*)d_in[0];
  const int*   src  = (const int*)  d_in[1];
  const int*   dst  = (const int*)  d_in[2];
  const float* vals = (const float*)d_in[3];
  const float* W1   = (const float*)d_in[4];
  const float* b1   = (const float*)d_in[5];
  const float* W2   = (const float*)d_in[6];
  const float* b2   = (const float*)d_in[7];
  const int M = in_sizes[0] / 256;   // 100000
  const int E = in_sizes[1];         // 1600000

  const int NSB = (M + 255) >> 8;    // 391 sub-buckets of 256 nodes

  // workspace layout
  int2* recs = (int2*)d_ws;                                  // NSB*LCAP*8B (~17.6MB)
  uint8_t* xw8 = (uint8_t*)(recs + (size_t)NSB * LCAP);      // M*128 fp8 (12.8MB)
  unsigned short* haccb = (unsigned short*)(xw8 + (size_t)M * 128); // M*128 bf16
  unsigned short* hwb   = haccb + (size_t)M * 128;           // M*64 bf16
  int* begA   = (int*)(hwb + (size_t)M * 64);                // M
  int* endA   = begA + M;                                    // M
  int* gcnt   = endA + M;                                    // 400
  short* W1bt = (short*)(gcnt + 400);                        // 256*128
  short* W2bt = W1bt + 256 * 128;                            // 128*64
  float* outf = (float*)d_out;

  const int gbin = (E + BCHUNK - 1) / BCHUNK;                // 196
  const int GB   = (M + 127) / 128;                          // 782

  prepw_k<<<128, 256, 0, stream>>>(W1, W2, W1bt, W2bt, gcnt);

  // fused: gemm1 || bin
  fused1_k<<<GB + gbin, 512, 0, stream>>>(x, W1bt, xw8, M, src, dst, vals,
                                          gcnt, recs, E, NSB, GB);
  sortsb_k<<<NSB, 256, 0, stream>>>(recs, gcnt, begA, endA, M);

  spmm1_k<<<(M + 15) / 16, 256, 0, stream>>>(begA, endA, recs, xw8, haccb, M);

  gemm2_k<<<(M + 127) / 128, 512, 0, stream>>>(haccb, b1, W2bt, hwb, M);
  spmm2_lsm_k<<<(M + 31) / 32, 256, 0, stream>>>(begA, endA, recs, hwb, b2, outf, M);
}

// Round 20
// 138.816 us; speedup vs baseline: 1.2038x; 1.0470x over previous
//
#include <hip/hip_runtime.h>
#include <stdint.h>

// GCN 2-layer forward.
// prepw(+gcnt zero, strided) -> fused[gemm1(W-in-LDS, A-upfront, fp8 out) || bin]
//   -> sortsb -> spmm1(fp8 gather) -> gemm2(W-in-LDS, fused relu+b1, fp8 out)
//   -> spmm2+lsm (fp8 gather)
// record format: x = val bits, y = src | (dst&255)<<17

typedef __attribute__((ext_vector_type(8))) short short8;
typedef __attribute__((ext_vector_type(8))) unsigned short ushort8;
typedef __attribute__((ext_vector_type(4))) float f32x4;
typedef __attribute__((ext_vector_type(2))) float f32x2;

#define BCHUNK 8192
#define LCAP 5632          // per-sub-bucket capacity (mean 4092, large margin)

// f32 -> bf16 bits (RNE)
static __device__ __forceinline__ uint32_t f2bu(float f) {
  uint32_t u = __float_as_uint(f);
  return (u + 0x7FFFu + ((u >> 16) & 1u)) >> 16;
}
static __device__ __forceinline__ float bu2f(unsigned short u) {
  return __uint_as_float(((uint32_t)u) << 16);
}

// 8 fp8(e4m3) -> 8 fma into a[8]
static __device__ __forceinline__ void fma8_fp8(float v, uint2 q, float (&a)[8]) {
  f32x2 p0 = __builtin_amdgcn_cvt_pk_f32_fp8((int)q.x, false);
  f32x2 p1 = __builtin_amdgcn_cvt_pk_f32_fp8((int)q.x, true);
  f32x2 p2 = __builtin_amdgcn_cvt_pk_f32_fp8((int)q.y, false);
  f32x2 p3 = __builtin_amdgcn_cvt_pk_f32_fp8((int)q.y, true);
  a[0] = fmaf(v, p0[0], a[0]); a[1] = fmaf(v, p0[1], a[1]);
  a[2] = fmaf(v, p1[0], a[2]); a[3] = fmaf(v, p1[1], a[3]);
  a[4] = fmaf(v, p2[0], a[4]); a[5] = fmaf(v, p2[1], a[5]);
  a[6] = fmaf(v, p3[0], a[6]); a[7] = fmaf(v, p3[1], a[7]);
}

// ---------------- weight prep (+ gcnt zero, strided — R12 lesson) ----------------
__global__ __launch_bounds__(256) void prepw_k(const float* __restrict__ W1,
                                               const float* __restrict__ W2,
                                               short* __restrict__ W1bt,
                                               short* __restrict__ W2bt,
                                               int* __restrict__ gcnt) {
  if (blockIdx.x == 0)
    for (int t = threadIdx.x; t < 400; t += 256) gcnt[t] = 0;
  int i = blockIdx.x * 256 + threadIdx.x;
  if (i < 256 * 128) {
    int k = i >> 7, c = i & 127;
    W1bt[c * 256 + k] = (short)f2bu(W1[i]);
  }
  if (i < 128 * 64) {
    int k = i >> 6, c = i & 63;
    W2bt[c * 128 + k] = (short)f2bu(W2[i]);
  }
}

// ---------------- fused: gemm1 (blocks < GB) | bin (blocks >= GB) ----------------
__global__ __launch_bounds__(512) void fused1_k(const float* __restrict__ X,
                                                const short* __restrict__ W1bt,
                                                uint8_t* __restrict__ X8, int M,
                                                const int* __restrict__ src,
                                                const int* __restrict__ dst,
                                                const float* __restrict__ vals,
                                                int* __restrict__ gcnt,
                                                int2* __restrict__ recs,
                                                int E, int NSB, int GB) {
  __shared__ short Ws[128][264];   // 67.6 KB (stride 132 dwords -> <=2-way aliasing)
  __shared__ int cnt[400];
  __shared__ int base[400];
  const int tid = threadIdx.x;

  if (blockIdx.x >= GB) {
    // ---------------- bin portion ----------------
    for (int t = tid; t < 400; t += 512) cnt[t] = 0;
    __syncthreads();
    int beg = (blockIdx.x - GB) * BCHUNK;
    int end = min(beg + BCHUNK, E);
    for (int i = beg + tid; i < end; i += 512) atomicAdd(&cnt[dst[i] >> 8], 1);
    __syncthreads();
    for (int t = tid; t < NSB; t += 512) {
      int c = cnt[t];
      base[t] = c ? atomicAdd(&gcnt[t], c) : 0;
      cnt[t] = 0;
    }
    __syncthreads();
    for (int i = beg + tid; i < end; i += 512) {
      int d = dst[i];
      int s2 = d >> 8;
      int pos = atomicAdd(&cnt[s2], 1);
      int2 r;
      r.x = __float_as_int(vals[i]);
      r.y = src[i] | ((d & 255) << 17);
      recs[(size_t)s2 * LCAP + base[s2] + pos] = r;
    }
    return;
  }

  // ---------------- gemm1 portion ----------------
  const int lane = tid & 63;
  const int wid = tid >> 6;            // 8 waves, 16 rows each
  const int bm = blockIdx.x * 128;
  const int l15 = lane & 15;
  const int lk8 = (lane >> 4) * 8;

  // stage whole W1bt [128 cols][256 k]: 4096 16B chunks, 8 per thread
#pragma unroll
  for (int i = 0; i < 8; ++i) {
    int idx = tid + i * 512;
    int r = idx >> 5;
    int kq = (idx & 31) * 8;
    *(short8*)&Ws[r][kq] = *(const short8*)&W1bt[r * 256 + kq];
  }

  const int arow = bm + wid * 16 + l15;
  const bool ok = arow < M;
  const float* xr = X + (size_t)arow * 256;

  // issue ALL 16 A-loads up front (static regs)
  float4 a[8][2];
#pragma unroll
  for (int kc = 0; kc < 8; ++kc) {
    if (ok) {
      a[kc][0] = *(const float4*)&xr[kc * 32 + lk8];
      a[kc][1] = *(const float4*)&xr[kc * 32 + lk8 + 4];
    } else {
      a[kc][0] = make_float4(0.f, 0.f, 0.f, 0.f);
      a[kc][1] = make_float4(0.f, 0.f, 0.f, 0.f);
    }
  }

  __syncthreads();                     // Ws ready (the ONLY barrier)

  f32x4 acc[8];
#pragma unroll
  for (int j = 0; j < 8; ++j) acc[j] = (f32x4)0.f;

#pragma unroll
  for (int kc = 0; kc < 8; ++kc) {
    short8 af;
    af[0] = (short)f2bu(a[kc][0].x); af[1] = (short)f2bu(a[kc][0].y);
    af[2] = (short)f2bu(a[kc][0].z); af[3] = (short)f2bu(a[kc][0].w);
    af[4] = (short)f2bu(a[kc][1].x); af[5] = (short)f2bu(a[kc][1].y);
    af[6] = (short)f2bu(a[kc][1].z); af[7] = (short)f2bu(a[kc][1].w);
#pragma unroll
    for (int ni = 0; ni < 8; ++ni) {
      short8 b = *(const short8*)&Ws[ni * 16 + l15][kc * 32 + lk8];
      acc[ni] = __builtin_amdgcn_mfma_f32_16x16x32_bf16(af, b, acc[ni], 0, 0, 0);
    }
  }
  // C/D: col = ni*16 + (lane&15), row = wid*16 + (lane>>4)*4 + j ; fp8 out
#pragma unroll
  for (int j = 0; j < 4; ++j) {
    int row = bm + wid * 16 + (lane >> 4) * 4 + j;
    if (row < M) {
#pragma unroll
      for (int ni = 0; ni < 8; ++ni) {
        int w = __builtin_amdgcn_cvt_pk_fp8_f32(acc[ni][j], 0.f, 0, false);
        X8[(size_t)row * 128 + ni * 16 + l15] = (uint8_t)(w & 0xFF);
      }
    }
  }
}

// ---------------- sortsb: per-sub-bucket counting sort (in place) ----------------
__global__ __launch_bounds__(256) void sortsb_k(int2* __restrict__ recs,
                                                const int* __restrict__ gcnt,
                                                int* __restrict__ begA,
                                                int* __restrict__ endA, int M) {
  __shared__ int2 lrec[LCAP];     // 45 KB
  __shared__ int cnt[256];
  __shared__ int sh[256];
  __shared__ int exc[256];
  __shared__ int cur[256];
  const int s = blockIdx.x;
  const int tid = threadIdx.x;
  int n = gcnt[s];
  if (n > LCAP) n = LCAP;
  int2* g = recs + (size_t)s * LCAP;
  cnt[tid] = 0;
  cur[tid] = 0;
  __syncthreads();
  for (int i = tid; i < n; i += 256) {
    int2 r = g[i];
    lrec[i] = r;
    atomicAdd(&cnt[(r.y >> 17) & 255], 1);
  }
  __syncthreads();
  int v = cnt[tid];
  sh[tid] = v;
  __syncthreads();
#pragma unroll
  for (int o = 1; o < 256; o <<= 1) {
    int t = (tid >= o) ? sh[tid - o] : 0;
    __syncthreads();
    sh[tid] += t;
    __syncthreads();
  }
  exc[tid] = sh[tid] - v;   // exclusive prefix
  __syncthreads();
  for (int i = tid; i < n; i += 256) {
    int2 r = lrec[i];
    int dlo = (r.y >> 17) & 255;
    int p = exc[dlo] + atomicAdd(&cur[dlo], 1);
    g[p] = r;
  }
  int node = s * 256 + tid;
  if (node < M) {
    int b = s * LCAP + exc[tid];
    begA[node] = b;
    endA[node] = b + v;
  }
}

// -------- GEMM2: hw8[M,64](fp8) = relu(Hb+b1) @ W2 — W-in-LDS, barrier-free --------
__global__ __launch_bounds__(512) void gemm2_k(const unsigned short* __restrict__ Hb,
                                               const float* __restrict__ b1,
                                               const short* __restrict__ W2bt,
                                               uint8_t* __restrict__ H8, int M) {
  __shared__ short Ws[64][136];    // 17.4 KB
  const int tid = threadIdx.x;
  const int lane = tid & 63;
  const int wid = tid >> 6;            // 8 waves, 16 rows each
  const int bm = blockIdx.x * 128;
  const int l15 = lane & 15;
  const int lk8 = (lane >> 4) * 8;

#pragma unroll
  for (int i = 0; i < 2; ++i) {
    int idx = tid + i * 512;
    int r = idx >> 4;
    int kq = (idx & 15) * 8;
    *(short8*)&Ws[r][kq] = *(const short8*)&W2bt[r * 128 + kq];
  }
  __syncthreads();

  const int arow = bm + wid * 16 + l15;
  const bool ok = arow < M;
  const unsigned short* hr = Hb + (size_t)arow * 128;

  f32x4 acc[4];
#pragma unroll
  for (int j = 0; j < 4; ++j) acc[j] = (f32x4)0.f;

#pragma unroll
  for (int kc = 0; kc < 4; ++kc) {
    float4 ba = *(const float4*)&b1[kc * 32 + lk8];
    float4 bb = *(const float4*)&b1[kc * 32 + lk8 + 4];
    short8 af = (short8)0;
    if (ok) {
      ushort8 hv = *(const ushort8*)&hr[kc * 32 + lk8];
      af[0] = (short)f2bu(fmaxf(bu2f(hv[0]) + ba.x, 0.f));
      af[1] = (short)f2bu(fmaxf(bu2f(hv[1]) + ba.y, 0.f));
      af[2] = (short)f2bu(fmaxf(bu2f(hv[2]) + ba.z, 0.f));
      af[3] = (short)f2bu(fmaxf(bu2f(hv[3]) + ba.w, 0.f));
      af[4] = (short)f2bu(fmaxf(bu2f(hv[4]) + bb.x, 0.f));
      af[5] = (short)f2bu(fmaxf(bu2f(hv[5]) + bb.y, 0.f));
      af[6] = (short)f2bu(fmaxf(bu2f(hv[6]) + bb.z, 0.f));
      af[7] = (short)f2bu(fmaxf(bu2f(hv[7]) + bb.w, 0.f));
    }
#pragma unroll
    for (int ni = 0; ni < 4; ++ni) {
      short8 b = *(const short8*)&Ws[ni * 16 + l15][kc * 32 + lk8];
      acc[ni] = __builtin_amdgcn_mfma_f32_16x16x32_bf16(af, b, acc[ni], 0, 0, 0);
    }
  }
  // fp8 epilogue (same pattern as gemm1's proven epilogue)
#pragma unroll
  for (int j = 0; j < 4; ++j) {
    int row = bm + wid * 16 + (lane >> 4) * 4 + j;
    if (row < M) {
#pragma unroll
      for (int ni = 0; ni < 4; ++ni) {
        int w = __builtin_amdgcn_cvt_pk_fp8_f32(acc[ni][j], 0.f, 0, false);
        H8[(size_t)row * 64 + ni * 16 + l15] = (uint8_t)(w & 0xFF);
      }
    }
  }
}

// ---------------- SpMM1: haccb[M,128](bf16) from fp8 gather, 16 thr/node ----------------
__global__ __launch_bounds__(256) void spmm1_k(const int* __restrict__ begA,
                                               const int* __restrict__ endA,
                                               const int2* __restrict__ edges,
                                               const uint8_t* __restrict__ X8,
                                               unsigned short* __restrict__ outb, int M) {
  int node = blockIdx.x * 16 + (threadIdx.x >> 4);
  int g = (threadIdx.x & 15) * 8;
  if (node >= M) return;
  int e = begA[node];
  const int end = endA[node];
  float a0[8], a1[8];
#pragma unroll
  for (int j = 0; j < 8; ++j) { a0[j] = 0.f; a1[j] = 0.f; }
  for (; e + 4 <= end; e += 4) {
    int2 e0 = edges[e], e1 = edges[e + 1], e2 = edges[e + 2], e3 = edges[e + 3];
    float v0 = __int_as_float(e0.x), v1 = __int_as_float(e1.x);
    float v2 = __int_as_float(e2.x), v3 = __int_as_float(e3.x);
    uint2 q0 = *(const uint2*)&X8[(size_t)(e0.y & 0x1FFFF) * 128 + g];
    uint2 q1 = *(const uint2*)&X8[(size_t)(e1.y & 0x1FFFF) * 128 + g];
    uint2 q2 = *(const uint2*)&X8[(size_t)(e2.y & 0x1FFFF) * 128 + g];
    uint2 q3 = *(const uint2*)&X8[(size_t)(e3.y & 0x1FFFF) * 128 + g];
    fma8_fp8(v0, q0, a0);
    fma8_fp8(v1, q1, a1);
    fma8_fp8(v2, q2, a0);
    fma8_fp8(v3, q3, a1);
  }
  for (; e < end; ++e) {
    int2 e0 = edges[e];
    float v0 = __int_as_float(e0.x);
    uint2 q0 = *(const uint2*)&X8[(size_t)(e0.y & 0x1FFFF) * 128 + g];
    fma8_fp8(v0, q0, a0);
  }
  ushort8 o;
#pragma unroll
  for (int j = 0; j < 8; ++j) o[j] = (unsigned short)f2bu(a0[j] + a1[j]);
  *(ushort8*)&outb[(size_t)node * 128 + g] = o;
}

// -------- SpMM2 + bias + log_softmax fused, 8 thr/node, fp8 gather --------
__global__ __launch_bounds__(256) void spmm2_lsm_k(const int* __restrict__ begA,
                                                   const int* __restrict__ endA,
                                                   const int2* __restrict__ edges,
                                                   const uint8_t* __restrict__ H8,
                                                   const float* __restrict__ b2,
                                                   float* __restrict__ out, int M) {
  int node = blockIdx.x * 32 + (threadIdx.x >> 3);
  int g = (threadIdx.x & 7) * 8;
  if (node >= M) return;
  int e = begA[node];
  const int end = endA[node];
  float a0[8], a1[8];
#pragma unroll
  for (int j = 0; j < 8; ++j) { a0[j] = 0.f; a1[j] = 0.f; }
  for (; e + 4 <= end; e += 4) {
    int2 e0 = edges[e], e1 = edges[e + 1], e2 = edges[e + 2], e3 = edges[e + 3];
    float v0 = __int_as_float(e0.x), v1 = __int_as_float(e1.x);
    float v2 = __int_as_float(e2.x), v3 = __int_as_float(e3.x);
    uint2 q0 = *(const uint2*)&H8[(size_t)(e0.y & 0x1FFFF) * 64 + g];
    uint2 q1 = *(const uint2*)&H8[(size_t)(e1.y & 0x1FFFF) * 64 + g];
    uint2 q2 = *(const uint2*)&H8[(size_t)(e2.y & 0x1FFFF) * 64 + g];
    uint2 q3 = *(const uint2*)&H8[(size_t)(e3.y & 0x1FFFF) * 64 + g];
    fma8_fp8(v0, q0, a0);
    fma8_fp8(v1, q1, a1);
    fma8_fp8(v2, q2, a0);
    fma8_fp8(v3, q3, a1);
  }
  for (; e < end; ++e) {
    int2 e0 = edges[e];
    float v0 = __int_as_float(e0.x);
    uint2 q0 = *(const uint2*)&H8[(size_t)(e0.y & 0x1FFFF) * 64 + g];
    fma8_fp8(v0, q0, a0);
  }
  float v[8];
  float4 ba = *(const float4*)&b2[g];
  float4 bb = *(const float4*)&b2[g + 4];
  v[0] = a0[0] + a1[0] + ba.x; v[1] = a0[1] + a1[1] + ba.y;
  v[2] = a0[2] + a1[2] + ba.z; v[3] = a0[3] + a1[3] + ba.w;
  v[4] = a0[4] + a1[4] + bb.x; v[5] = a0[5] + a1[5] + bb.y;
  v[6] = a0[6] + a1[6] + bb.z; v[7] = a0[7] + a1[7] + bb.w;
  float m = v[0];
#pragma unroll
  for (int j = 1; j < 8; ++j) m = fmaxf(m, v[j]);
#pragma unroll
  for (int o = 1; o < 8; o <<= 1) m = fmaxf(m, __shfl_xor(m, o, 64));
  float s = 0.f;
#pragma unroll
  for (int j = 0; j < 8; ++j) s += expf(v[j] - m);
#pragma unroll
  for (int o = 1; o < 8; o <<= 1) s += __shfl_xor(s, o, 64);
  float lse = m + logf(s);
  float4 r0 = make_float4(v[0] - lse, v[1] - lse, v[2] - lse, v[3] - lse);
  float4 r1 = make_float4(v[4] - lse, v[5] - lse, v[6] - lse, v[7] - lse);
  *(float4*)&out[(size_t)node * 64 + g] = r0;
  *(float4*)&out[(size_t)node * 64 + g + 4] = r1;
}

extern "C" void kernel_launch(void* const* d_in, const int* in_sizes, int n_in,
                              void* d_out, int out_size, void* d_ws, size_t ws_size,
                              hipStream_t stream) {
  const float* x    = (const float*)d_in[0];
  const int*   src  = (const int*)  d_in[1];
  const int*   dst  = (const int*)  d_in[2];
  const float* vals = (const float*)d_in[3];
  const float* W1   = (const float*)d_in[4];
  const float* b1   = (const float*)d_in[5];
  const float* W2   = (const float*)d_in[6];
  const float* b2   = (const float*)d_in[7];
  const int M = in_sizes[0] / 256;   // 100000
  const int E = in_sizes[1];         // 1600000

  const int NSB = (M + 255) >> 8;    // 391 sub-buckets of 256 nodes

  // workspace layout
  int2* recs = (int2*)d_ws;                                  // NSB*LCAP*8B (~17.6MB)
  uint8_t* xw8 = (uint8_t*)(recs + (size_t)NSB * LCAP);      // M*128 fp8 (12.8MB)
  unsigned short* haccb = (unsigned short*)(xw8 + (size_t)M * 128); // M*128 bf16
  uint8_t* hw8 = (uint8_t*)(haccb + (size_t)M * 128);        // M*64 fp8 (6.4MB)
  int* begA   = (int*)(hw8 + (size_t)M * 64);                // M
  int* endA   = begA + M;                                    // M
  int* gcnt   = endA + M;                                    // 400
  short* W1bt = (short*)(gcnt + 400);                        // 256*128
  short* W2bt = W1bt + 256 * 128;                            // 128*64
  float* outf = (float*)d_out;

  const int gbin = (E + BCHUNK - 1) / BCHUNK;                // 196
  const int GB   = (M + 127) / 128;                          // 782

  prepw_k<<<128, 256, 0, stream>>>(W1, W2, W1bt, W2bt, gcnt);

  // fused: gemm1 || bin
  fused1_k<<<GB + gbin, 512, 0, stream>>>(x, W1bt, xw8, M, src, dst, vals,
                                          gcnt, recs, E, NSB, GB);
  sortsb_k<<<NSB, 256, 0, stream>>>(recs, gcnt, begA, endA, M);

  spmm1_k<<<(M + 15) / 16, 256, 0, stream>>>(begA, endA, recs, xw8, haccb, M);

  gemm2_k<<<(M + 127) / 128, 512, 0, stream>>>(haccb, b1, W2bt, hw8, M);
  spmm2_lsm_k<<<(M + 31) / 32, 256, 0, stream>>>(begA, endA, recs, hw8, b2, outf, M);
}